// Round 1
// baseline (3221.885 us; speedup 1.0000x reference)
//
#include <hip/hip_runtime.h>

#define N 4096
#define NTHREADS 1024
#define IOU_THR 0.55f

// wsum lives in global memory (only thread 0 reads/writes it; write-before-read
// is guaranteed within each launch, so no init needed => deterministic).
__device__ float g_wsum[N * 4];

__global__ __launch_bounds__(NTHREADS) void wbf_kernel(
    const float* __restrict__ boxes,   // [16,256,6]
    const float* __restrict__ offs,    // [16,2]
    float* __restrict__ out)           // [1000,6]
{
  __shared__ float4 s_mbox[N];                  // 64 KB
  __shared__ float  s_cls[N];                   // 16 KB
  __shared__ float  s_ssum[N];                  // 16 KB
  __shared__ float  s_cnt[N];                   // 16 KB
  __shared__ unsigned long long s_keys[N];      // 32 KB
  __shared__ int s_min[2];
  __shared__ int s_num;

  const int tid = threadIdx.x;

  // ---- per-launch init (harness does NOT re-poison between replays) ----
  for (int j = tid; j < N; j += NTHREADS) s_cnt[j] = 0.0f;
  if (tid == 0) { s_num = 0; s_min[0] = 0x7fffffff; s_min[1] = 0x7fffffff; }

  // preload det 0 (uniform across threads)
  float bx1, by1, bx2, by2, sc, lb;
  {
    float ox = offs[0], oy = offs[1];
    bx1 = boxes[0] + ox; by1 = boxes[1] + oy;
    bx2 = boxes[2] + ox; by2 = boxes[3] + oy;
    sc = boxes[4]; lb = boxes[5];
  }

  // ---- sequential WBF scan ----
  for (int i = 0; i < N; ++i) {
    // prefetch next det (uniform scalar loads overlap the compare phase)
    int ii = (i + 1 < N) ? (i + 1) : (N - 1);
    const float* br = boxes + (size_t)ii * 6;
    int p = ii >> 8;
    float ox = offs[2 * p], oy = offs[2 * p + 1];
    float nx1 = br[0] + ox, ny1 = br[1] + oy;
    float nx2 = br[2] + ox, ny2 = br[3] + oy;
    float nsc = br[4], nlb = br[5];

    __syncthreads();                 // (A) prev-iter state updates visible
    int nm = s_num;
    float aA = (bx2 - bx1) * (by2 - by1);

    int mymin = 0x7fffffff;
    for (int c = tid; c < nm; c += NTHREADS) {
      float4 m = s_mbox[c];
      // conservative gate: any-overlap requires |corner delta| < 56 (all widths <= 56)
      if (fabsf(m.x - bx1) < 60.0f && fabsf(m.y - by1) < 60.0f && s_cls[c] == lb) {
        float xx1 = fmaxf(m.x, bx1), yy1 = fmaxf(m.y, by1);
        float xx2 = fminf(m.z, bx2), yy2 = fminf(m.w, by2);
        float iw = fmaxf(xx2 - xx1, 0.0f), ih = fmaxf(yy2 - yy1, 0.0f);
        float inter = iw * ih;
        float aB = (m.z - m.x) * (m.w - m.y);
        float uni = aA + aB - inter;
        if (uni > 0.0f) {
          float iou = inter / uni;
          if (iou > IOU_THR) mymin = min(mymin, c);
        }
      }
    }
    if (mymin != 0x7fffffff) atomicMin(&s_min[i & 1], mymin);
    __syncthreads();                 // (B) reduction complete
    int mn = s_min[i & 1];

    if (tid == 0) {
      s_min[(i + 1) & 1] = 0x7fffffff;   // reset the OTHER slot for next iter
      bool has = (mn != 0x7fffffff);
      int idx = has ? mn : nm;
      float w0, w1, w2, w3, ss, ct;
      if (has) {
        w0 = g_wsum[idx * 4 + 0]; w1 = g_wsum[idx * 4 + 1];
        w2 = g_wsum[idx * 4 + 2]; w3 = g_wsum[idx * 4 + 3];
        ss = s_ssum[idx]; ct = s_cnt[idx];
      } else { w0 = w1 = w2 = w3 = 0.0f; ss = 0.0f; ct = 0.0f; }
      w0 += sc * bx1; w1 += sc * by1; w2 += sc * bx2; w3 += sc * by2;
      ss += sc; ct += 1.0f;
      g_wsum[idx * 4 + 0] = w0; g_wsum[idx * 4 + 1] = w1;
      g_wsum[idx * 4 + 2] = w2; g_wsum[idx * 4 + 3] = w3;
      s_ssum[idx] = ss; s_cnt[idx] = ct;
      s_mbox[idx] = make_float4(w0 / ss, w1 / ss, w2 / ss, w3 / ss);
      s_cls[idx] = lb;
      if (!has) s_num = nm + 1;
    }

    bx1 = nx1; by1 = ny1; bx2 = nx2; by2 = ny2; sc = nsc; lb = nlb;
  }

  // ---- scoring + sortable keys: (score_bits | signbit)<<32 | ~index ----
  __syncthreads();
  for (int j = tid; j < N; j += NTHREADS) {
    float ct = s_cnt[j];
    unsigned int lo = ~(unsigned int)j;            // lower index wins ties
    unsigned long long key;
    if (ct > 0.0f) {
      float sco = s_ssum[j] / fmaxf(ct, 1.0f);     // bitwise == reference score
      unsigned int b = __float_as_uint(sco) | 0x80000000u;  // sco >= 0
      key = ((unsigned long long)b << 32) | lo;
    } else {
      // sort_key = -1.0f  ->  mapped ~bits(-1.0f) = 0x407FFFFF < any valid key
      key = (0x407FFFFFull << 32) | lo;
    }
    s_keys[j] = key;
  }
  __syncthreads();

  // ---- bitonic sort, descending, 4096 u64 keys ----
  for (int k = 2; k <= N; k <<= 1) {
    for (int j = k >> 1; j > 0; j >>= 1) {
      #pragma unroll
      for (int w = 0; w < N / NTHREADS; ++w) {
        int a0 = tid + (w << 10);
        int l = a0 ^ j;
        if (l > a0) {
          unsigned long long a = s_keys[a0], b = s_keys[l];
          bool desc = ((a0 & k) == 0);
          bool sw = desc ? (a < b) : (a > b);
          if (sw) { s_keys[a0] = b; s_keys[l] = a; }
        }
      }
      __syncthreads();
    }
  }

  // ---- emit top-1000 rows ----
  if (tid < 1000) {
    unsigned long long key = s_keys[tid];
    unsigned int hi = (unsigned int)(key >> 32);
    float* o = out + tid * 6;
    if (hi & 0x80000000u) {
      int j = (int)(~(unsigned int)key);
      float4 m = s_mbox[j];
      o[0] = m.x; o[1] = m.y; o[2] = m.z; o[3] = m.w;
      o[4] = __uint_as_float(hi & 0x7fffffffu);
      o[5] = s_cls[j];
    } else {
      o[0] = 0.0f; o[1] = 0.0f; o[2] = 0.0f;
      o[3] = 0.0f; o[4] = 0.0f; o[5] = 0.0f;
    }
  }
}

extern "C" void kernel_launch(void* const* d_in, const int* in_sizes, int n_in,
                              void* d_out, int out_size, void* d_ws, size_t ws_size,
                              hipStream_t stream) {
  const float* boxes = (const float*)d_in[0];
  const float* offs  = (const float*)d_in[1];
  float* out = (float*)d_out;
  hipLaunchKernelGGL(wbf_kernel, dim3(1), dim3(NTHREADS), 0, stream,
                     boxes, offs, out);
}

// Round 3
// 2354.561 us; speedup vs baseline: 1.3684x; 1.3684x over previous
//
#include <hip/hip_runtime.h>

#define N 4096
#define NT 1024
#define BATCH 64
#define KCAND 8
#define IOU_THR 0.55f
#define CPT 4   // clusters per thread = N / NT

__global__ __launch_bounds__(NT) void wbf_kernel(
    const float* __restrict__ boxes,   // [16,256,6]
    const float* __restrict__ offs,    // [16,2]
    float* __restrict__ out)           // [1000,6]
{
  // ---- LDS: 163,344 B (limit 163,840) ----
  __shared__ float4 s_mbox[N];                 // 64 KB merged boxes
  __shared__ float4 s_wsum[N];                 // 64 KB weighted sums (aliased as sort keys later)
  __shared__ float  s_ssum[N];                 // 16 KB
  __shared__ unsigned short s_cnt[N];          //  8 KB
  __shared__ unsigned char  s_cls[N];          //  4 KB
  __shared__ unsigned long long s_dirty[64];   // 512 B
  __shared__ uint4 s_cand4[BATCH];             //  1 KB (8 x u16 candidates per box)
  __shared__ int   s_ccnt[BATCH];              // 256 B
  __shared__ float s_batch[BATCH][6];          // 1.5 KB staged boxes (offsets applied)
  __shared__ unsigned s_bgate[BATCH];          // 256 B packed (cls<<12|xq)<<16 | yq
  __shared__ int s_min[2];
  __shared__ int s_num, s_resume;

  const int tid = threadIdx.x;

  if (tid < 64) s_dirty[tid] = 0ull;
  if (tid == 0) { s_num = 0; s_resume = BATCH; s_min[0] = 0x7fffffff; s_min[1] = 0x7fffffff; }

  // ================= batched WBF scan =================
  for (int t0 = 0; t0 < N; t0 += BATCH) {
    // ---- stage batch boxes + clear candidate counters ----
    if (tid < BATCH * 6) {
      int b = tid / 6, f = tid % 6;
      int gi = t0 + b;
      float v = boxes[(size_t)gi * 6 + f];
      if (f < 4) v += offs[((gi >> 8) << 1) + (f & 1)];
      s_batch[b][f] = v;
    } else if (tid < BATCH * 6 + BATCH) {
      s_ccnt[tid - BATCH * 6] = 0;
    }
    __syncthreads();

    int nm0 = s_num;

    // ---- build gate words; load per-thread cluster gate cache ----
    if (tid < BATCH) {
      int qx = (int)s_batch[tid][0];
      int qy = (int)s_batch[tid][1];
      int lb = (int)s_batch[tid][5];
      s_bgate[tid] = ((unsigned)((lb << 12) | qx) << 16) | (unsigned)qy;
    }
    int my_n = 0;
    int chi[CPT], clo[CPT];
    #pragma unroll
    for (int k = 0; k < CPT; ++k) {
      int c = tid + k * NT;
      if (c < nm0) {
        float2 mxy = *(const float2*)&s_mbox[c];
        chi[k] = ((int)s_cls[c] << 12) | (int)mxy.x;
        clo[k] = (int)mxy.y;
        my_n = k + 1;
      }
    }
    __syncthreads();

    // ---- phase 1: candidate generation vs clean pre-batch clusters ----
    if (my_n > 0) {
      for (int b = 0; b < BATCH; ++b) {
        unsigned g = s_bgate[b];
        unsigned hb = g >> 16, lbo = g & 0xFFFFu;
        #pragma unroll
        for (int k = 0; k < CPT; ++k) {
          if (k < my_n) {
            unsigned dx = __usad((unsigned)chi[k], hb, 0u);
            unsigned dy = __usad((unsigned)clo[k], lbo, 0u);
            if (dx <= 60u && dy <= 60u) {     // pass => same class & spatially near
              int c = tid + k * NT;
              float4 m = s_mbox[c];
              float2 q1 = *(const float2*)&s_batch[b][0];
              float2 q2 = *(const float2*)&s_batch[b][2];
              float xx1 = fmaxf(m.x, q1.x), yy1 = fmaxf(m.y, q1.y);
              float xx2 = fminf(m.z, q2.x), yy2 = fminf(m.w, q2.y);
              float iw = fmaxf(xx2 - xx1, 0.0f), ih = fmaxf(yy2 - yy1, 0.0f);
              float inter = iw * ih;
              float aA = (q2.x - q1.x) * (q2.y - q1.y);
              float aB = (m.z - m.x) * (m.w - m.y);
              float uni = aA + aB - inter;
              if (uni > 0.0f && inter / uni > IOU_THR) {
                int pos = atomicAdd(&s_ccnt[b], 1);
                if (pos < KCAND) ((unsigned short*)&s_cand4[b])[pos] = (unsigned short)c;
              }
            }
          }
        }
      }
    }
    __syncthreads();

    // ---- resolution: wave 0 serial over 64 boxes; modified state in registers ----
    if (tid < 64) {
      const int lane = tid;
      int nmod = 0, nnew = 0, resume = BATCH;
      int e_valid = 0, e_idx = 0x7fffffff, e_ct = 0;
      unsigned char e_cls = 0;
      float e_m0=0,e_m1=0,e_m2=0,e_m3=0, e_w0=0,e_w1=0,e_w2=0,e_w3=0, e_ss=0;

      for (int b = 0; b < BATCH; ++b) {
        int cc = s_ccnt[b];
        if (cc > KCAND) { resume = b; break; }
        float2 q1 = *(const float2*)&s_batch[b][0];
        float2 q2 = *(const float2*)&s_batch[b][2];
        float2 q3 = *(const float2*)&s_batch[b][4];
        float bx1 = q1.x, by1 = q1.y, bx2 = q2.x, by2 = q2.y;
        float sc = q3.x;
        unsigned char lb = (unsigned char)q3.y;

        int v = 0x7fffffff;
        if (lane < cc) {                      // divergent LDS read: safe (no shfl)
          int ci = (int)((const unsigned short*)&s_cand4[b])[lane];
          if (!((s_dirty[ci >> 6] >> (ci & 63)) & 1ull)) v = ci;
        }
        if (e_valid && e_cls == lb &&
            fabsf(e_m0 - bx1) < 60.0f && fabsf(e_m1 - by1) < 60.0f) {
          float xx1 = fmaxf(e_m0, bx1), yy1 = fmaxf(e_m1, by1);
          float xx2 = fminf(e_m2, bx2), yy2 = fminf(e_m3, by2);
          float iw = fmaxf(xx2 - xx1, 0.0f), ih = fmaxf(yy2 - yy1, 0.0f);
          float inter = iw * ih;
          float aA = (bx2 - bx1) * (by2 - by1);
          float aB = (e_m2 - e_m0) * (e_m3 - e_m1);
          float uni = aA + aB - inter;
          if (uni > 0.0f && inter / uni > IOU_THR) v = min(v, e_idx);
        }
        unsigned long long ball = __ballot(v != 0x7fffffff);
        int mn = 0x7fffffff;
        if (ball != 0ull) {                   // uniform branch; all lanes active below
          if (__popcll(ball) == 1) {
            mn = __shfl(v, (int)__builtin_ctzll(ball));   // full convergence: legal
          } else {
            int t = v;
            for (int o = 32; o; o >>= 1) t = min(t, __shfl_xor(t, o));
            mn = t;
          }
        }

        if (mn == 0x7fffffff) {
          if (lane == nmod) {                 // new cluster
            e_valid = 1; e_idx = nm0 + nnew; e_cls = lb;
            e_w0 = sc * bx1; e_w1 = sc * by1; e_w2 = sc * bx2; e_w3 = sc * by2;
            e_ss = sc; e_ct = 1;
            e_m0 = e_w0 / e_ss; e_m1 = e_w1 / e_ss; e_m2 = e_w2 / e_ss; e_m3 = e_w3 / e_ss;
          }
          nmod++; nnew++;
        } else {
          bool mine = e_valid && (e_idx == mn);
          unsigned long long mb = __ballot(mine);
          if (mb == 0ull) {
            if (lane == nmod) {               // pull clean cluster into modified set
              e_valid = 1; e_idx = mn; e_cls = lb;
              float4 w = s_wsum[mn];
              float ss = s_ssum[mn]; int ct = (int)s_cnt[mn];
              e_w0 = w.x + sc * bx1; e_w1 = w.y + sc * by1;
              e_w2 = w.z + sc * bx2; e_w3 = w.w + sc * by2;
              e_ss = ss + sc; e_ct = ct + 1;
              e_m0 = e_w0 / e_ss; e_m1 = e_w1 / e_ss; e_m2 = e_w2 / e_ss; e_m3 = e_w3 / e_ss;
              atomicOr(&s_dirty[mn >> 6], 1ull << (mn & 63));
            }
            nmod++;
          } else {
            if (mine) {                       // merge into already-modified cluster
              e_w0 += sc * bx1; e_w1 += sc * by1; e_w2 += sc * bx2; e_w3 += sc * by2;
              e_ss += sc; e_ct += 1;
              e_m0 = e_w0 / e_ss; e_m1 = e_w1 / e_ss; e_m2 = e_w2 / e_ss; e_m3 = e_w3 / e_ss;
            }
          }
        }
      }
      // writeback modified clusters; clear dirty bits
      if (e_valid) {
        s_mbox[e_idx] = make_float4(e_m0, e_m1, e_m2, e_m3);
        s_wsum[e_idx] = make_float4(e_w0, e_w1, e_w2, e_w3);
        s_ssum[e_idx] = e_ss;
        s_cnt[e_idx]  = (unsigned short)e_ct;
        s_cls[e_idx]  = e_cls;
      }
      s_dirty[lane] = 0ull;
      if (lane == 0) { s_num = nm0 + nnew; s_resume = resume; }
    }
    __syncthreads();

    // ---- exact serial fallback (candidate overflow; probability ~0) ----
    int rs = s_resume;
    if (rs < BATCH) {
      for (int i = rs; i < BATCH; ++i) {
        float bx1 = s_batch[i][0], by1 = s_batch[i][1];
        float bx2 = s_batch[i][2], by2 = s_batch[i][3];
        float sc  = s_batch[i][4];
        unsigned char lb = (unsigned char)s_batch[i][5];
        int nm = s_num;
        float aA = (bx2 - bx1) * (by2 - by1);
        int mymin = 0x7fffffff;
        for (int c = tid; c < nm; c += NT) {
          float4 m = s_mbox[c];
          if (fabsf(m.x - bx1) < 60.0f && fabsf(m.y - by1) < 60.0f && s_cls[c] == lb) {
            float xx1 = fmaxf(m.x, bx1), yy1 = fmaxf(m.y, by1);
            float xx2 = fminf(m.z, bx2), yy2 = fminf(m.w, by2);
            float iw = fmaxf(xx2 - xx1, 0.0f), ih = fmaxf(yy2 - yy1, 0.0f);
            float inter = iw * ih;
            float aB = (m.z - m.x) * (m.w - m.y);
            float uni = aA + aB - inter;
            if (uni > 0.0f && inter / uni > IOU_THR) mymin = min(mymin, c);
          }
        }
        if (mymin != 0x7fffffff) atomicMin(&s_min[i & 1], mymin);
        __syncthreads();
        int mn = s_min[i & 1];
        if (tid == 0) {
          s_min[(i + 1) & 1] = 0x7fffffff;   // reset slot for iter i+1 (barrier-separated)
          bool has = (mn != 0x7fffffff);
          int idx = has ? mn : nm;
          float w0, w1, w2, w3, ss; int ct;
          if (has) {
            float4 w = s_wsum[idx];
            w0 = w.x; w1 = w.y; w2 = w.z; w3 = w.w;
            ss = s_ssum[idx]; ct = (int)s_cnt[idx];
          } else { w0 = w1 = w2 = w3 = 0.0f; ss = 0.0f; ct = 0; }
          w0 += sc * bx1; w1 += sc * by1; w2 += sc * bx2; w3 += sc * by2;
          ss += sc; ct += 1;
          s_wsum[idx] = make_float4(w0, w1, w2, w3);
          s_ssum[idx] = ss; s_cnt[idx] = (unsigned short)ct;
          s_mbox[idx] = make_float4(w0 / ss, w1 / ss, w2 / ss, w3 / ss);
          s_cls[idx] = lb;
          if (!has) s_num = nm + 1;
        }
        __syncthreads();
      }
      if (tid == 0) { s_min[0] = 0x7fffffff; s_min[1] = 0x7fffffff; }
    }
  }

  // ================= scoring + sort keys (keys alias s_wsum) =================
  __syncthreads();
  unsigned long long* s_keys = (unsigned long long*)s_wsum;
  int num = s_num;
  for (int j = tid; j < N; j += NT) {
    unsigned int lo = ~(unsigned int)j;              // lower index wins ties
    unsigned long long key;
    if (j < num) {
      float ct = (float)s_cnt[j];
      float sco = s_ssum[j] / fmaxf(ct, 1.0f);       // pure adds+div: bitwise == reference
      unsigned int bb = __float_as_uint(sco) | 0x80000000u;
      key = ((unsigned long long)bb << 32) | lo;
    } else {
      key = (0x407FFFFFull << 32) | lo;              // mapped bits of -1.0f sort key
    }
    s_keys[j] = key;
  }
  __syncthreads();

  // ---- bitonic sort, descending, 4096 u64 keys ----
  for (int k = 2; k <= N; k <<= 1) {
    for (int j = k >> 1; j > 0; j >>= 1) {
      #pragma unroll
      for (int w = 0; w < N / NT; ++w) {
        int a0 = tid + (w << 10);
        int l = a0 ^ j;
        if (l > a0) {
          unsigned long long a = s_keys[a0], bq = s_keys[l];
          bool desc = ((a0 & k) == 0);
          bool sw = desc ? (a < bq) : (a > bq);
          if (sw) { s_keys[a0] = bq; s_keys[l] = a; }
        }
      }
      __syncthreads();
    }
  }

  // ---- emit top-1000 rows ----
  if (tid < 1000) {
    unsigned long long key = s_keys[tid];
    unsigned int hi = (unsigned int)(key >> 32);
    float* o = out + (size_t)tid * 6;
    if (hi & 0x80000000u) {
      int j = (int)(~(unsigned int)key);
      float4 m = s_mbox[j];
      o[0] = m.x; o[1] = m.y; o[2] = m.z; o[3] = m.w;
      o[4] = __uint_as_float(hi & 0x7fffffffu);
      o[5] = (float)s_cls[j];
    } else {
      o[0] = 0.0f; o[1] = 0.0f; o[2] = 0.0f;
      o[3] = 0.0f; o[4] = 0.0f; o[5] = 0.0f;
    }
  }
}

extern "C" void kernel_launch(void* const* d_in, const int* in_sizes, int n_in,
                              void* d_out, int out_size, void* d_ws, size_t ws_size,
                              hipStream_t stream) {
  const float* boxes = (const float*)d_in[0];
  const float* offs  = (const float*)d_in[1];
  float* out = (float*)d_out;
  hipLaunchKernelGGL(wbf_kernel, dim3(1), dim3(NT), 0, stream, boxes, offs, out);
}

// Round 4
// 2328.834 us; speedup vs baseline: 1.3835x; 1.0110x over previous
//
#include <hip/hip_runtime.h>

#define N 4096
#define NT 1024
#define BATCH 64
#define KCAND 8
#define IOU_THR 0.55f
#define CPT 4   // clusters per thread = N / NT

__device__ __forceinline__ float rl_f(float v, int lane) {
  return __int_as_float(__builtin_amdgcn_readlane(__float_as_int(v), lane));
}
__device__ __forceinline__ int rl_i(int v, int lane) {
  return __builtin_amdgcn_readlane(v, lane);
}

__global__ __launch_bounds__(NT) void wbf_kernel(
    const float* __restrict__ boxes,   // [16,256,6]
    const float* __restrict__ offs,    // [16,2]
    float* __restrict__ out)           // [1000,6]
{
  // ---- LDS: 163,344 B (limit 163,840) ----
  __shared__ float4 s_mbox[N];                 // 64 KB merged boxes
  __shared__ float4 s_wsum[N];                 // 64 KB weighted sums (aliased as sort keys later)
  __shared__ float  s_ssum[N];                 // 16 KB
  __shared__ unsigned short s_cnt[N];          //  8 KB
  __shared__ unsigned char  s_cls[N];          //  4 KB
  __shared__ unsigned long long s_dirty[64];   // 512 B
  __shared__ uint4 s_cand4[BATCH];             //  1 KB (8 x u16 candidates per box)
  __shared__ int   s_ccnt[BATCH];              // 256 B
  __shared__ float s_batch[BATCH][6];          // 1.5 KB staged boxes (offsets applied)
  __shared__ unsigned s_bgate[BATCH];          // 256 B packed (cls<<12|xq)<<16 | yq
  __shared__ int s_min[2];
  __shared__ int s_num, s_resume;

  const int tid = threadIdx.x;

  if (tid < 64) s_dirty[tid] = 0ull;
  if (tid == 0) { s_num = 0; s_resume = BATCH; s_min[0] = 0x7fffffff; s_min[1] = 0x7fffffff; }

  // ================= batched WBF scan =================
  for (int t0 = 0; t0 < N; t0 += BATCH) {
    // ---- stage batch boxes + clear candidate counters ----
    if (tid < BATCH * 6) {
      int b = tid / 6, f = tid % 6;
      int gi = t0 + b;
      float v = boxes[(size_t)gi * 6 + f];
      if (f < 4) v += offs[((gi >> 8) << 1) + (f & 1)];
      s_batch[b][f] = v;
    } else if (tid < BATCH * 6 + BATCH) {
      s_ccnt[tid - BATCH * 6] = 0;
    }
    __syncthreads();

    int nm0 = s_num;

    // ---- build gate words; load per-thread cluster gate cache ----
    if (tid < BATCH) {
      int qx = (int)s_batch[tid][0];
      int qy = (int)s_batch[tid][1];
      int lb = (int)s_batch[tid][5];
      s_bgate[tid] = ((unsigned)((lb << 12) | qx) << 16) | (unsigned)qy;
    }
    int my_n = 0;
    int chi[CPT], clo[CPT];
    #pragma unroll
    for (int k = 0; k < CPT; ++k) {
      int c = tid + k * NT;
      if (c < nm0) {
        float2 mxy = *(const float2*)&s_mbox[c];
        chi[k] = ((int)s_cls[c] << 12) | (int)mxy.x;
        clo[k] = (int)mxy.y;
        my_n = k + 1;
      }
    }
    __syncthreads();

    // ---- phase 1: candidate generation vs clean pre-batch clusters ----
    if (my_n > 0) {
      for (int b = 0; b < BATCH; ++b) {
        unsigned g = s_bgate[b];
        unsigned hb = g >> 16, lbo = g & 0xFFFFu;
        #pragma unroll
        for (int k = 0; k < CPT; ++k) {
          if (k < my_n) {
            unsigned dx = __usad((unsigned)chi[k], hb, 0u);
            unsigned dy = __usad((unsigned)clo[k], lbo, 0u);
            if (dx <= 60u && dy <= 60u) {     // pass => same class & spatially near
              int c = tid + k * NT;
              float4 m = s_mbox[c];
              float2 q1 = *(const float2*)&s_batch[b][0];
              float2 q2 = *(const float2*)&s_batch[b][2];
              float xx1 = fmaxf(m.x, q1.x), yy1 = fmaxf(m.y, q1.y);
              float xx2 = fminf(m.z, q2.x), yy2 = fminf(m.w, q2.y);
              float iw = fmaxf(xx2 - xx1, 0.0f), ih = fmaxf(yy2 - yy1, 0.0f);
              float inter = iw * ih;
              float aA = (q2.x - q1.x) * (q2.y - q1.y);
              float aB = (m.z - m.x) * (m.w - m.y);
              float uni = aA + aB - inter;
              if (uni > 0.0f && inter / uni > IOU_THR) {
                int pos = atomicAdd(&s_ccnt[b], 1);
                if (pos < KCAND) ((unsigned short*)&s_cand4[b])[pos] = (unsigned short)c;
              }
            }
          }
        }
      }
    }
    __syncthreads();

    // ---- resolution: wave 0, register-resident; zero LDS in common path ----
    if (tid < 64) {
      const int lane = tid;
      // batch-wide parallel prefetch into lane registers (one shot)
      float p0 = s_batch[lane][0], p1 = s_batch[lane][1], p2 = s_batch[lane][2];
      float p3 = s_batch[lane][3], p4 = s_batch[lane][4], p5 = s_batch[lane][5];
      int   cc_l = s_ccnt[lane];
      uint4 cp_l = s_cand4[lane];
      unsigned long long anycand = __ballot(cc_l > 0);
      unsigned long long ovf     = __ballot(cc_l > KCAND);

      int nmod = 0, nnew = 0, resume = BATCH;
      int e_valid = 0, e_idx = 0x7fffffff, e_ct = 0;
      float e_cls = -1.0f;
      float e_m0=0,e_m1=0,e_m2=0,e_m3=0, e_w0=0,e_w1=0,e_w2=0,e_w3=0, e_ss=0;

      for (int b = 0; b < BATCH; ++b) {
        if ((ovf >> b) & 1ull) { resume = b; break; }
        // uniform broadcast via readlane (lane index b is uniform; ignores exec)
        float bx1 = rl_f(p0, b), by1 = rl_f(p1, b);
        float bx2 = rl_f(p2, b), by2 = rl_f(p3, b);
        float sc  = rl_f(p4, b), lbf = rl_f(p5, b);

        int v = 0x7fffffff;
        // step 1: recheck modified/new clusters with CURRENT state (all lanes)
        if (e_valid && e_cls == lbf &&
            fabsf(e_m0 - bx1) < 60.0f && fabsf(e_m1 - by1) < 60.0f) {
          float xx1 = fmaxf(e_m0, bx1), yy1 = fmaxf(e_m1, by1);
          float xx2 = fminf(e_m2, bx2), yy2 = fminf(e_m3, by2);
          float iw = fmaxf(xx2 - xx1, 0.0f), ih = fmaxf(yy2 - yy1, 0.0f);
          float inter = iw * ih;
          float aA = (bx2 - bx1) * (by2 - by1);
          float aB = (e_m2 - e_m0) * (e_m3 - e_m1);
          float uni = aA + aB - inter;
          if (uni > 0.0f && inter / uni > IOU_THR) v = e_idx;
        }
        // step 2: clean candidates (rare path, gated by uniform bitmask)
        if ((anycand >> b) & 1ull) {
          int cc = rl_i(cc_l, b);
          unsigned w0 = (unsigned)rl_i((int)cp_l.x, b);
          unsigned w1 = (unsigned)rl_i((int)cp_l.y, b);
          unsigned w2 = (unsigned)rl_i((int)cp_l.z, b);
          unsigned w3 = (unsigned)rl_i((int)cp_l.w, b);
          if (lane < cc) {
            unsigned w = (lane >= 6) ? w3 : (lane >= 4) ? w2 : (lane >= 2) ? w1 : w0;
            int ci = (int)((w >> ((lane & 1) * 16)) & 0xffffu);
            if (!((s_dirty[ci >> 6] >> (ci & 63)) & 1ull)) v = min(v, ci);
          }
        }
        unsigned long long ball = __ballot(v != 0x7fffffff);
        if (ball == 0ull) {
          if (lane == nmod) {                 // new cluster
            e_valid = 1; e_idx = nm0 + nnew; e_cls = lbf;
            e_w0 = sc * bx1; e_w1 = sc * by1; e_w2 = sc * bx2; e_w3 = sc * by2;
            e_ss = sc; e_ct = 1;
            e_m0 = e_w0 / e_ss; e_m1 = e_w1 / e_ss; e_m2 = e_w2 / e_ss; e_m3 = e_w3 / e_ss;
          }
          nmod++; nnew++;
        } else {
          int mn;
          if (__popcll(ball) == 1) {
            mn = rl_i(v, (int)__builtin_ctzll(ball));
          } else {
            int t = v;
            for (int o = 32; o; o >>= 1) t = min(t, __shfl_xor(t, o));
            mn = t;
          }
          bool mine = e_valid && (e_idx == mn);
          unsigned long long mb = __ballot(mine);
          if (mb == 0ull) {
            if (lane == nmod) {               // pull clean cluster into modified set
              e_valid = 1; e_idx = mn; e_cls = lbf;
              float4 w = s_wsum[mn];
              float ss = s_ssum[mn]; int ct = (int)s_cnt[mn];
              e_w0 = w.x + sc * bx1; e_w1 = w.y + sc * by1;
              e_w2 = w.z + sc * bx2; e_w3 = w.w + sc * by2;
              e_ss = ss + sc; e_ct = ct + 1;
              e_m0 = e_w0 / e_ss; e_m1 = e_w1 / e_ss; e_m2 = e_w2 / e_ss; e_m3 = e_w3 / e_ss;
              atomicOr(&s_dirty[mn >> 6], 1ull << (mn & 63));
            }
            nmod++;
          } else {
            if (mine) {                       // merge into already-modified cluster
              e_w0 += sc * bx1; e_w1 += sc * by1; e_w2 += sc * bx2; e_w3 += sc * by2;
              e_ss += sc; e_ct += 1;
              e_m0 = e_w0 / e_ss; e_m1 = e_w1 / e_ss; e_m2 = e_w2 / e_ss; e_m3 = e_w3 / e_ss;
            }
          }
        }
      }
      // writeback modified clusters; clear dirty bits
      if (e_valid) {
        s_mbox[e_idx] = make_float4(e_m0, e_m1, e_m2, e_m3);
        s_wsum[e_idx] = make_float4(e_w0, e_w1, e_w2, e_w3);
        s_ssum[e_idx] = e_ss;
        s_cnt[e_idx]  = (unsigned short)e_ct;
        s_cls[e_idx]  = (unsigned char)e_cls;
      }
      s_dirty[lane] = 0ull;
      if (lane == 0) { s_num = nm0 + nnew; s_resume = resume; }
    }
    __syncthreads();

    // ---- exact serial fallback (candidate overflow; probability ~0) ----
    int rs = s_resume;
    if (rs < BATCH) {
      for (int i = rs; i < BATCH; ++i) {
        float bx1 = s_batch[i][0], by1 = s_batch[i][1];
        float bx2 = s_batch[i][2], by2 = s_batch[i][3];
        float sc  = s_batch[i][4];
        unsigned char lb = (unsigned char)s_batch[i][5];
        int nm = s_num;
        float aA = (bx2 - bx1) * (by2 - by1);
        int mymin = 0x7fffffff;
        for (int c = tid; c < nm; c += NT) {
          float4 m = s_mbox[c];
          if (fabsf(m.x - bx1) < 60.0f && fabsf(m.y - by1) < 60.0f && s_cls[c] == lb) {
            float xx1 = fmaxf(m.x, bx1), yy1 = fmaxf(m.y, by1);
            float xx2 = fminf(m.z, bx2), yy2 = fminf(m.w, by2);
            float iw = fmaxf(xx2 - xx1, 0.0f), ih = fmaxf(yy2 - yy1, 0.0f);
            float inter = iw * ih;
            float aB = (m.z - m.x) * (m.w - m.y);
            float uni = aA + aB - inter;
            if (uni > 0.0f && inter / uni > IOU_THR) mymin = min(mymin, c);
          }
        }
        if (mymin != 0x7fffffff) atomicMin(&s_min[i & 1], mymin);
        __syncthreads();
        int mn = s_min[i & 1];
        if (tid == 0) {
          s_min[(i + 1) & 1] = 0x7fffffff;
          bool has = (mn != 0x7fffffff);
          int idx = has ? mn : nm;
          float w0, w1, w2, w3, ss; int ct;
          if (has) {
            float4 w = s_wsum[idx];
            w0 = w.x; w1 = w.y; w2 = w.z; w3 = w.w;
            ss = s_ssum[idx]; ct = (int)s_cnt[idx];
          } else { w0 = w1 = w2 = w3 = 0.0f; ss = 0.0f; ct = 0; }
          w0 += sc * bx1; w1 += sc * by1; w2 += sc * bx2; w3 += sc * by2;
          ss += sc; ct += 1;
          s_wsum[idx] = make_float4(w0, w1, w2, w3);
          s_ssum[idx] = ss; s_cnt[idx] = (unsigned short)ct;
          s_mbox[idx] = make_float4(w0 / ss, w1 / ss, w2 / ss, w3 / ss);
          s_cls[idx] = lb;
          if (!has) s_num = nm + 1;
        }
        __syncthreads();
      }
      if (tid == 0) { s_min[0] = 0x7fffffff; s_min[1] = 0x7fffffff; }
    }
  }

  // ================= scoring + sort keys (keys alias s_wsum) =================
  __syncthreads();
  unsigned long long* s_keys = (unsigned long long*)s_wsum;
  int num = s_num;
  for (int j = tid; j < N; j += NT) {
    unsigned int lo = ~(unsigned int)j;              // lower index wins ties
    unsigned long long key;
    if (j < num) {
      float ct = (float)s_cnt[j];
      float sco = s_ssum[j] / fmaxf(ct, 1.0f);       // pure adds+div: bitwise == reference
      unsigned int bb = __float_as_uint(sco) | 0x80000000u;
      key = ((unsigned long long)bb << 32) | lo;
    } else {
      key = (0x407FFFFFull << 32) | lo;              // mapped bits of -1.0f sort key
    }
    s_keys[j] = key;
  }
  __syncthreads();

  // ---- bitonic sort, descending, 4096 u64 keys ----
  for (int k = 2; k <= N; k <<= 1) {
    for (int j = k >> 1; j > 0; j >>= 1) {
      #pragma unroll
      for (int w = 0; w < N / NT; ++w) {
        int a0 = tid + (w << 10);
        int l = a0 ^ j;
        if (l > a0) {
          unsigned long long a = s_keys[a0], bq = s_keys[l];
          bool desc = ((a0 & k) == 0);
          bool sw = desc ? (a < bq) : (a > bq);
          if (sw) { s_keys[a0] = bq; s_keys[l] = a; }
        }
      }
      __syncthreads();
    }
  }

  // ---- emit top-1000 rows ----
  if (tid < 1000) {
    unsigned long long key = s_keys[tid];
    unsigned int hi = (unsigned int)(key >> 32);
    float* o = out + (size_t)tid * 6;
    if (hi & 0x80000000u) {
      int j = (int)(~(unsigned int)key);
      float4 m = s_mbox[j];
      o[0] = m.x; o[1] = m.y; o[2] = m.z; o[3] = m.w;
      o[4] = __uint_as_float(hi & 0x7fffffffu);
      o[5] = (float)s_cls[j];
    } else {
      o[0] = 0.0f; o[1] = 0.0f; o[2] = 0.0f;
      o[3] = 0.0f; o[4] = 0.0f; o[5] = 0.0f;
    }
  }
}

extern "C" void kernel_launch(void* const* d_in, const int* in_sizes, int n_in,
                              void* d_out, int out_size, void* d_ws, size_t ws_size,
                              hipStream_t stream) {
  const float* boxes = (const float*)d_in[0];
  const float* offs  = (const float*)d_in[1];
  float* out = (float*)d_out;
  hipLaunchKernelGGL(wbf_kernel, dim3(1), dim3(NT), 0, stream, boxes, offs, out);
}

// Round 5
// 1070.761 us; speedup vs baseline: 3.0090x; 2.1749x over previous
//
#include <hip/hip_runtime.h>

#define N 4096
#define NT 1024
#define BATCH 64
#define KCAND 4
#define IOU_THR 0.55f
#define CPT 4   // clusters per thread = N / NT
#define INF 0x7fffffff

__device__ __forceinline__ float rl_f(float v, int lane) {
  return __int_as_float(__builtin_amdgcn_readlane(__float_as_int(v), lane));
}
__device__ __forceinline__ int rl_i(int v, int lane) {
  return __builtin_amdgcn_readlane(v, lane);
}

__global__ __launch_bounds__(NT) void wbf_kernel(
    const float* __restrict__ boxes,   // [16,256,6]
    const float* __restrict__ offs,    // [16,2]
    float* __restrict__ out)           // [1000,6]
{
  // ---- LDS ~163,332 B (limit 163,840) ----
  __shared__ float4 s_mbox[N];                 // 64 KB merged boxes
  __shared__ float4 s_wsum[N];                 // 64 KB weighted sums (sort keys alias later)
  __shared__ float  s_ssum[N];                 // 16 KB
  __shared__ unsigned short s_cnt[N];          //  8 KB
  __shared__ unsigned char  s_cls[N];          //  4 KB
  __shared__ unsigned long long s_dirty[64];   // 512 B
  __shared__ uint2 s_cand2[BATCH];             // 512 B (4 x u16 candidates per box)
  __shared__ int   s_ccnt[BATCH];              // 256 B
  __shared__ float s_batch[BATCH][6];          // 1.5 KB staged boxes (offsets applied)
  __shared__ unsigned s_bgate[BATCH];          // 256 B packed (cls<<12|x1)<<16 | y1
  __shared__ unsigned long long s_pm[BATCH];   // 512 B within-batch pair-match masks (j<b)
  __shared__ int s_min[2];
  __shared__ int s_num, s_resume;

  const int tid = threadIdx.x;

  if (tid < 64) s_dirty[tid] = 0ull;
  if (tid == 0) { s_num = 0; s_resume = BATCH; s_min[0] = INF; s_min[1] = INF; }

  // ================= batched WBF scan =================
  for (int t0 = 0; t0 < N; t0 += BATCH) {
    // ---- stage batch boxes; clear candidate counters and pair masks ----
    if (tid < BATCH * 6) {
      int b = tid / 6, f = tid % 6;
      int gi = t0 + b;
      float v = boxes[(size_t)gi * 6 + f];
      if (f < 4) v += offs[((gi >> 8) << 1) + (f & 1)];
      s_batch[b][f] = v;
    } else if (tid < BATCH * 7) {
      s_ccnt[tid - BATCH * 6] = 0;
    } else if (tid < BATCH * 8) {
      s_pm[tid - BATCH * 7] = 0ull;
    }
    __syncthreads();

    int nm0 = s_num;

    // ---- build gate words; load per-thread cluster gate cache ----
    if (tid < BATCH) {
      int qx = (int)s_batch[tid][0];
      int qy = (int)s_batch[tid][1];
      int lb = (int)s_batch[tid][5];
      s_bgate[tid] = ((unsigned)((lb << 12) | qx) << 16) | (unsigned)qy;
    }
    int my_n = 0;
    int chi[CPT], clo[CPT];
    #pragma unroll
    for (int k = 0; k < CPT; ++k) {
      int c = tid + k * NT;
      if (c < nm0) {
        float2 mxy = *(const float2*)&s_mbox[c];
        chi[k] = ((int)s_cls[c] << 12) | (int)mxy.x;
        clo[k] = (int)mxy.y;
        my_n = k + 1;
      }
    }
    __syncthreads();

    // ---- phase 1: exact candidates vs clean pre-batch clusters ----
    if (my_n > 0) {
      for (int b = 0; b < BATCH; ++b) {
        unsigned g = s_bgate[b];
        unsigned hb = g >> 16, lbo = g & 0xFFFFu;
        #pragma unroll
        for (int k = 0; k < CPT; ++k) {
          if (k < my_n) {
            unsigned dx = __usad((unsigned)chi[k], hb, 0u);
            unsigned dy = __usad((unsigned)clo[k], lbo, 0u);
            if (dx <= 60u && dy <= 60u) {
              int c = tid + k * NT;
              float4 m = s_mbox[c];
              float2 q1 = *(const float2*)&s_batch[b][0];
              float2 q2 = *(const float2*)&s_batch[b][2];
              float xx1 = fmaxf(m.x, q1.x), yy1 = fmaxf(m.y, q1.y);
              float xx2 = fminf(m.z, q2.x), yy2 = fminf(m.w, q2.y);
              float iw = fmaxf(xx2 - xx1, 0.0f), ih = fmaxf(yy2 - yy1, 0.0f);
              float inter = iw * ih;
              float aA = (q2.x - q1.x) * (q2.y - q1.y);
              float aB = (m.z - m.x) * (m.w - m.y);
              float uni = aA + aB - inter;
              if (uni > 0.0f && inter / uni > IOU_THR) {
                int pos = atomicAdd(&s_ccnt[b], 1);
                if (pos < KCAND) ((unsigned short*)&s_cand2[b])[pos] = (unsigned short)c;
              }
            }
          }
        }
      }
    }
    // ---- phase 1.5: within-batch pairwise exact-IoU masks (j < b) ----
    #pragma unroll
    for (int q = 0; q < 4; ++q) {
      int p = tid + q * NT;
      int bb = p >> 6, jj = p & 63;
      if (jj < bb) {
        unsigned gb = s_bgate[bb], gj = s_bgate[jj];
        unsigned dx = __usad(gb >> 16, gj >> 16, 0u);
        unsigned dy = __usad(gb & 0xFFFFu, gj & 0xFFFFu, 0u);
        if (dx <= 60u && dy <= 60u) {
          float ax1 = s_batch[bb][0], ay1 = s_batch[bb][1];
          float ax2 = s_batch[bb][2], ay2 = s_batch[bb][3];
          float jx1 = s_batch[jj][0], jy1 = s_batch[jj][1];
          float jx2 = s_batch[jj][2], jy2 = s_batch[jj][3];
          float xx1 = fmaxf(ax1, jx1), yy1 = fmaxf(ay1, jy1);
          float xx2 = fminf(ax2, jx2), yy2 = fminf(ay2, jy2);
          float iw = fmaxf(xx2 - xx1, 0.0f), ih = fmaxf(yy2 - yy1, 0.0f);
          float inter = iw * ih;
          float aA = (ax2 - ax1) * (ay2 - ay1);
          float aB = (jx2 - jx1) * (jy2 - jy1);
          float uni = aA + aB - inter;
          if (uni > 0.0f && inter / uni > IOU_THR)
            atomicOr(&s_pm[bb], 1ull << jj);
        }
      }
    }
    __syncthreads();

    // ---- resolution: wave 0, flagged boxes only; bulk singleton materialization ----
    if (tid < 64) {
      const int lane = tid;
      float p0 = s_batch[lane][0], p1 = s_batch[lane][1], p2 = s_batch[lane][2];
      float p3 = s_batch[lane][3], p4 = s_batch[lane][4], p5 = s_batch[lane][5];
      int   cc_l = s_ccnt[lane];
      uint2 cp_l = s_cand2[lane];
      unsigned long long pm_l = s_pm[lane];
      int pml_lo = (int)(unsigned)pm_l, pml_hi = (int)(unsigned)(pm_l >> 32);

      unsigned long long anycand = __ballot(cc_l > 0);
      unsigned long long OVF = __ballot(cc_l > KCAND);
      unsigned long long F = __ballot(cc_l > 0 || pm_l != 0ull);
      int rs = BATCH;
      if (OVF) rs = (int)__builtin_ctzll(OVF);
      unsigned long long lowrs = (rs >= 64) ? ~0ull : ((1ull << rs) - 1ull);
      unsigned long long rem = F & lowrs;
      unsigned long long NEWM = ~F & lowrs;   // will-create-new-cluster mask
      unsigned long long consumed = 0ull;

      int nmod = 0;
      int e_valid = 0, e_idx = INF, e_ct = 0;
      float e_cls = -1.0f;
      float e_m0=0,e_m1=0,e_m2=0,e_m3=0, e_w0=0,e_w1=0,e_w2=0,e_w3=0, e_ss=0;

      while (rem) {
        int b = (int)__builtin_ctzll(rem);
        rem &= rem - 1ull;
        float bx1 = rl_f(p0, b), by1 = rl_f(p1, b);
        float bx2 = rl_f(p2, b), by2 = rl_f(p3, b);
        float sc  = rl_f(p4, b), lbf = rl_f(p5, b);

        int v = INF;
        // (a) recheck modified entries vs CURRENT state
        if (e_valid && e_cls == lbf &&
            fabsf(e_m0 - bx1) < 60.0f && fabsf(e_m1 - by1) < 60.0f) {
          float xx1 = fmaxf(e_m0, bx1), yy1 = fmaxf(e_m1, by1);
          float xx2 = fminf(e_m2, bx2), yy2 = fminf(e_m3, by2);
          float iw = fmaxf(xx2 - xx1, 0.0f), ih = fmaxf(yy2 - yy1, 0.0f);
          float inter = iw * ih;
          float aA = (bx2 - bx1) * (by2 - by1);
          float aB = (e_m2 - e_m0) * (e_m3 - e_m1);
          float uni = aA + aB - inter;
          if (uni > 0.0f && inter / uni > IOU_THR) v = e_idx;
        }
        // (b) clean pre-batch candidates (dirty-filtered)
        if ((anycand >> b) & 1ull) {
          int cc = rl_i(cc_l, b);
          unsigned w0 = (unsigned)rl_i((int)cp_l.x, b);
          unsigned w1 = (unsigned)rl_i((int)cp_l.y, b);
          if (lane < cc) {
            unsigned w = (lane >= 2) ? w1 : w0;
            int ci = (int)((w >> ((lane & 1) * 16)) & 0xFFFFu);
            if (!((s_dirty[ci >> 6] >> (ci & 63)) & 1ull)) v = min(v, ci);
          }
        }
        unsigned long long ball = __ballot(v != INF);
        int mn = INF;
        if (ball != 0ull) {
          if (__popcll(ball) == 1) {
            mn = rl_i(v, (int)__builtin_ctzll(ball));
          } else {
            int t = v;
            for (int o = 32; o; o >>= 1) t = min(t, __shfl_xor(t, o));
            mn = t;
          }
        }
        // (c) within-batch singleton pair candidate (uniform)
        unsigned long long pc =
            (((unsigned long long)(unsigned)rl_i(pml_hi, b)) << 32) |
            (unsigned long long)(unsigned)rl_i(pml_lo, b);
        pc &= ~F & ~consumed;
        int pj = 64, pairidx = INF;
        if (pc) {
          pj = (int)__builtin_ctzll(pc);
          pairidx = nm0 + (int)__builtin_popcountll(NEWM & ((1ull << pj) - 1ull));
        }
        if (pairidx < mn) mn = pairidx;

        if (mn == INF) {
          // new cluster
          int nidx = nm0 + (int)__builtin_popcountll(NEWM & ((1ull << b) - 1ull));
          NEWM |= 1ull << b;
          if (lane == nmod) {
            e_valid = 1; e_idx = nidx; e_cls = lbf;
            e_w0 = sc * bx1; e_w1 = sc * by1; e_w2 = sc * bx2; e_w3 = sc * by2;
            e_ss = sc; e_ct = 1;
            e_m0 = e_w0 / e_ss; e_m1 = e_w1 / e_ss; e_m2 = e_w2 / e_ss; e_m3 = e_w3 / e_ss;
          }
          nmod++;
          // no detection needed: later boxes matching this singleton are pair-flagged
        } else {
          bool mine = e_valid && (e_idx == mn);
          unsigned long long mb = __ballot(mine);
          int owner;
          if (mb != 0ull) {
            owner = (int)__builtin_ctzll(mb);
            if (mine) {
              e_w0 += sc * bx1; e_w1 += sc * by1; e_w2 += sc * bx2; e_w3 += sc * by2;
              e_ss += sc; e_ct += 1;
              e_m0 = e_w0 / e_ss; e_m1 = e_w1 / e_ss; e_m2 = e_w2 / e_ss; e_m3 = e_w3 / e_ss;
            }
          } else if (mn < nm0) {
            owner = nmod;
            if (lane == nmod) {                 // pull clean cluster
              e_valid = 1; e_idx = mn; e_cls = lbf;
              float4 w = s_wsum[mn];
              float ss = s_ssum[mn]; int ct = (int)s_cnt[mn];
              e_w0 = w.x + sc * bx1; e_w1 = w.y + sc * by1;
              e_w2 = w.z + sc * bx2; e_w3 = w.w + sc * by2;
              e_ss = ss + sc; e_ct = ct + 1;
              e_m0 = e_w0 / e_ss; e_m1 = e_w1 / e_ss; e_m2 = e_w2 / e_ss; e_m3 = e_w3 / e_ss;
              atomicOr(&s_dirty[mn >> 6], 1ull << (mn & 63));
            }
            nmod++;
          } else {
            owner = nmod;                       // pull unflagged singleton pj
            consumed |= 1ull << pj;
            if (lane == nmod) {
              float jx1 = rl_f(p0, pj), jy1 = rl_f(p1, pj);
              float jx2 = rl_f(p2, pj), jy2 = rl_f(p3, pj);
              float jsc = rl_f(p4, pj);
              e_valid = 1; e_idx = mn; e_cls = lbf;
              e_w0 = jsc * jx1 + sc * bx1; e_w1 = jsc * jy1 + sc * by1;
              e_w2 = jsc * jx2 + sc * bx2; e_w3 = jsc * jy2 + sc * by2;
              e_ss = jsc + sc; e_ct = 2;
              e_m0 = e_w0 / e_ss; e_m1 = e_w1 / e_ss; e_m2 = e_w2 / e_ss; e_m3 = e_w3 / e_ss;
            }
            nmod++;
          }
          // ---- detection: did this merge's moved box capture a later unflagged box? ----
          float nx1 = rl_f(e_m0, owner), ny1 = rl_f(e_m1, owner);
          float nx2 = rl_f(e_m2, owner), ny2 = rl_f(e_m3, owner);
          bool dp = false;
          if (p5 == lbf) {
            float xx1 = fmaxf(nx1, p0), yy1 = fmaxf(ny1, p1);
            float xx2 = fminf(nx2, p2), yy2 = fminf(ny2, p3);
            float iw = fmaxf(xx2 - xx1, 0.0f), ih = fmaxf(yy2 - yy1, 0.0f);
            float inter = iw * ih;
            float aA = (p2 - p0) * (p3 - p1);
            float aB = (nx2 - nx1) * (ny2 - ny1);
            float uni = aA + aB - inter;
            dp = (uni > 0.0f) && (inter / uni > IOU_THR);
          }
          unsigned long long det = __ballot(dp);
          unsigned long long himask = (b >= 63) ? 0ull : (~0ull << (b + 1));
          det &= ~F & ~consumed & lowrs & himask;
          if (det) { F |= det; rem |= det; NEWM &= ~det; }
        }
      }

      // writeback modified entries
      if (e_valid) {
        s_mbox[e_idx] = make_float4(e_m0, e_m1, e_m2, e_m3);
        s_wsum[e_idx] = make_float4(e_w0, e_w1, e_w2, e_w3);
        s_ssum[e_idx] = e_ss;
        s_cnt[e_idx]  = (unsigned short)e_ct;
        s_cls[e_idx]  = (unsigned char)e_cls;
      }
      // bulk-materialize untouched singletons (parallel across lanes)
      {
        unsigned long long selfbit = 1ull << lane;
        if (NEWM & ~F & ~consumed & selfbit) {
          int idx = nm0 + (int)__builtin_popcountll(NEWM & (selfbit - 1ull));
          float w0 = p4 * p0, w1 = p4 * p1, w2 = p4 * p2, w3 = p4 * p3;
          s_wsum[idx] = make_float4(w0, w1, w2, w3);
          s_ssum[idx] = p4;
          s_cnt[idx]  = 1;
          s_cls[idx]  = (unsigned char)p5;
          s_mbox[idx] = make_float4(w0 / p4, w1 / p4, w2 / p4, w3 / p4);
        }
      }
      s_dirty[lane] = 0ull;
      if (lane == 0) {
        s_num = nm0 + (int)__builtin_popcountll(NEWM);
        s_resume = rs;
      }
    }
    __syncthreads();

    // ---- exact serial fallback (candidate overflow; probability ~0) ----
    int rs = s_resume;
    if (rs < BATCH) {
      for (int i = rs; i < BATCH; ++i) {
        float bx1 = s_batch[i][0], by1 = s_batch[i][1];
        float bx2 = s_batch[i][2], by2 = s_batch[i][3];
        float sc  = s_batch[i][4];
        unsigned char lb = (unsigned char)s_batch[i][5];
        int nm = s_num;
        float aA = (bx2 - bx1) * (by2 - by1);
        int mymin = INF;
        for (int c = tid; c < nm; c += NT) {
          float4 m = s_mbox[c];
          if (fabsf(m.x - bx1) < 60.0f && fabsf(m.y - by1) < 60.0f && s_cls[c] == lb) {
            float xx1 = fmaxf(m.x, bx1), yy1 = fmaxf(m.y, by1);
            float xx2 = fminf(m.z, bx2), yy2 = fminf(m.w, by2);
            float iw = fmaxf(xx2 - xx1, 0.0f), ih = fmaxf(yy2 - yy1, 0.0f);
            float inter = iw * ih;
            float aB = (m.z - m.x) * (m.w - m.y);
            float uni = aA + aB - inter;
            if (uni > 0.0f && inter / uni > IOU_THR) mymin = min(mymin, c);
          }
        }
        if (mymin != INF) atomicMin(&s_min[i & 1], mymin);
        __syncthreads();
        int mn = s_min[i & 1];
        if (tid == 0) {
          s_min[(i + 1) & 1] = INF;
          bool has = (mn != INF);
          int idx = has ? mn : nm;
          float w0, w1, w2, w3, ss; int ct;
          if (has) {
            float4 w = s_wsum[idx];
            w0 = w.x; w1 = w.y; w2 = w.z; w3 = w.w;
            ss = s_ssum[idx]; ct = (int)s_cnt[idx];
          } else { w0 = w1 = w2 = w3 = 0.0f; ss = 0.0f; ct = 0; }
          w0 += sc * bx1; w1 += sc * by1; w2 += sc * bx2; w3 += sc * by2;
          ss += sc; ct += 1;
          s_wsum[idx] = make_float4(w0, w1, w2, w3);
          s_ssum[idx] = ss; s_cnt[idx] = (unsigned short)ct;
          s_mbox[idx] = make_float4(w0 / ss, w1 / ss, w2 / ss, w3 / ss);
          s_cls[idx] = lb;
          if (!has) s_num = nm + 1;
        }
        __syncthreads();
      }
      if (tid == 0) { s_min[0] = INF; s_min[1] = INF; }
    }
  }

  // ================= scoring + sort keys (keys alias s_wsum) =================
  __syncthreads();
  unsigned long long* s_keys = (unsigned long long*)s_wsum;
  int num = s_num;
  for (int j = tid; j < N; j += NT) {
    unsigned int lo = ~(unsigned int)j;              // lower index wins ties
    unsigned long long key;
    if (j < num) {
      float ct = (float)s_cnt[j];
      float sco = s_ssum[j] / fmaxf(ct, 1.0f);       // bitwise == reference score
      unsigned int bb = __float_as_uint(sco) | 0x80000000u;
      key = ((unsigned long long)bb << 32) | lo;
    } else {
      key = (0x407FFFFFull << 32) | lo;              // mapped bits of -1.0f sort key
    }
    s_keys[j] = key;
  }
  __syncthreads();

  // ---- bitonic sort, descending, 4096 u64 keys ----
  for (int k = 2; k <= N; k <<= 1) {
    for (int j = k >> 1; j > 0; j >>= 1) {
      #pragma unroll
      for (int w = 0; w < N / NT; ++w) {
        int a0 = tid + (w << 10);
        int l = a0 ^ j;
        if (l > a0) {
          unsigned long long a = s_keys[a0], bq = s_keys[l];
          bool desc = ((a0 & k) == 0);
          bool sw = desc ? (a < bq) : (a > bq);
          if (sw) { s_keys[a0] = bq; s_keys[l] = a; }
        }
      }
      __syncthreads();
    }
  }

  // ---- emit top-1000 rows ----
  if (tid < 1000) {
    unsigned long long key = s_keys[tid];
    unsigned int hi = (unsigned int)(key >> 32);
    float* o = out + (size_t)tid * 6;
    if (hi & 0x80000000u) {
      int j = (int)(~(unsigned int)key);
      float4 m = s_mbox[j];
      o[0] = m.x; o[1] = m.y; o[2] = m.z; o[3] = m.w;
      o[4] = __uint_as_float(hi & 0x7FFFFFFFu);
      o[5] = (float)s_cls[j];
    } else {
      o[0] = 0.0f; o[1] = 0.0f; o[2] = 0.0f;
      o[3] = 0.0f; o[4] = 0.0f; o[5] = 0.0f;
    }
  }
}

extern "C" void kernel_launch(void* const* d_in, const int* in_sizes, int n_in,
                              void* d_out, int out_size, void* d_ws, size_t ws_size,
                              hipStream_t stream) {
  const float* boxes = (const float*)d_in[0];
  const float* offs  = (const float*)d_in[1];
  float* out = (float*)d_out;
  hipLaunchKernelGGL(wbf_kernel, dim3(1), dim3(NT), 0, stream, boxes, offs, out);
}

// Round 7
// 307.706 us; speedup vs baseline: 10.4707x; 3.4798x over previous
//
#include <hip/hip_runtime.h>

#define N 4096
#define NT 1024
#define BATCH 64
#define KCAND 8
#define IOU_THR 0.55f
#define INF 0x7fffffff
#define NBINS 14
#define NBKT 42     // 3 classes * 14 x-bins of 256px
#define BCAP 320

__device__ float4 g_wsum[N];   // weighted sums; always written before read per launch

__device__ __forceinline__ float rl_f(float v, int lane) {
  return __int_as_float(__builtin_amdgcn_readlane(__float_as_int(v), lane));
}
__device__ __forceinline__ int rl_i(int v, int lane) {
  return __builtin_amdgcn_readlane(v, lane);
}

__global__ __launch_bounds__(NT) void wbf_kernel(
    const float* __restrict__ boxes,   // [16,256,6]
    const float* __restrict__ offs,    // [16,2]
    float* __restrict__ out)           // [1000,6]
{
  // ---- LDS ~121.3 KB (limit 160 KB) ----
  __shared__ float4 s_mbox[N];                   // 64 KB (sort keys alias later)
  __shared__ float  s_ssum[N];                   // 16 KB
  __shared__ unsigned short s_cc[N];             //  8 KB  cnt | cls<<14
  __shared__ unsigned short s_bkt[NBKT][BCAP];   // 26.25 KB cluster-index buckets
  __shared__ int s_bktlen[NBKT];
  __shared__ unsigned long long s_dirty[64];
  __shared__ uint4 s_cand4[BATCH];               // 8 x u16 candidates per box
  __shared__ int   s_ccnt[BATCH];
  __shared__ float s_batch[BATCH][6];
  __shared__ unsigned s_bgate[BATCH];            // (cls<<12|x)<<16 | y  (phase 1.5)
  __shared__ unsigned long long s_pm[BATCH];
  __shared__ int s_min[2];
  __shared__ int s_num, s_resume, s_ovf;

  const int tid = threadIdx.x;

  if (tid < 64) s_dirty[tid] = 0ull;
  if (tid < NBKT) s_bktlen[tid] = 0;
  if (tid == 0) { s_num = 0; s_resume = BATCH; s_ovf = 0; s_min[0] = INF; s_min[1] = INF; }

  // ================= batched WBF scan =================
  for (int t0 = 0; t0 < N; t0 += BATCH) {
    // ---- stage batch boxes; clear candidate counters and pair masks ----
    if (tid < BATCH * 6) {
      int b = tid / 6, f = tid % 6;
      int gi = t0 + b;
      float v = boxes[(size_t)gi * 6 + f];
      if (f < 4) v += offs[((gi >> 8) << 1) + (f & 1)];
      s_batch[b][f] = v;
    } else if (tid < BATCH * 7) {
      s_ccnt[tid - BATCH * 6] = 0;
    } else if (tid < BATCH * 8) {
      s_pm[tid - BATCH * 7] = 0ull;
    }
    __syncthreads();

    int nm0 = s_num;
    if (tid < BATCH) {
      int qx = (int)s_batch[tid][0];
      int qy = (int)s_batch[tid][1];
      int lb = (int)s_batch[tid][5];
      s_bgate[tid] = ((unsigned)((lb << 12) | qx) << 16) | (unsigned)qy;
    }
    __syncthreads();

    // ---- phase 1: candidates vs clean pre-batch clusters (bucketed) ----
    int use_linear = s_ovf;
    if (!use_linear) {
      int b = tid >> 4, sl = tid & 15;        // 16 threads per box
      float qx1 = s_batch[b][0], qy1 = s_batch[b][1];
      float qx2 = s_batch[b][2], qy2 = s_batch[b][3];
      int cls = (int)s_batch[b][5];
      float aA = (qx2 - qx1) * (qy2 - qy1);
      int bb = ((int)qx1) >> 8;
      int jlo = bb > 0 ? bb - 1 : 0;
      int jhi = bb < NBINS - 1 ? bb + 1 : NBINS - 1;
      for (int j = jlo; j <= jhi; ++j) {
        int bk = cls * NBINS + j;
        int len = s_bktlen[bk]; if (len > BCAP) len = BCAP;
        for (int e = sl; e < len; e += 16) {
          int c = (int)s_bkt[bk][e];
          float4 m = s_mbox[c];
          if (fabsf(m.x - qx1) < 60.0f && fabsf(m.y - qy1) < 60.0f) {
            float xx1 = fmaxf(m.x, qx1), yy1 = fmaxf(m.y, qy1);
            float xx2 = fminf(m.z, qx2), yy2 = fminf(m.w, qy2);
            float iw = fmaxf(xx2 - xx1, 0.0f), ih = fmaxf(yy2 - yy1, 0.0f);
            float inter = iw * ih;
            float aB = (m.z - m.x) * (m.w - m.y);
            float uni = aA + aB - inter;
            if (uni > 0.0f && inter / uni > IOU_THR) {
              int pos = atomicAdd(&s_ccnt[b], 1);
              if (pos < KCAND) ((unsigned short*)&s_cand4[b])[pos] = (unsigned short)c;
            }
          }
        }
      }
    } else {
      // exact linear fallback (bucket overflow happened earlier)
      for (int c = tid; c < nm0; c += NT) {
        float4 m = s_mbox[c];
        int mcls = (int)(s_cc[c] >> 14);
        float aB = (m.z - m.x) * (m.w - m.y);
        for (int b2 = 0; b2 < BATCH; ++b2) {
          float qx1 = s_batch[b2][0], qy1 = s_batch[b2][1];
          if (fabsf(m.x - qx1) < 60.0f && fabsf(m.y - qy1) < 60.0f &&
              mcls == (int)s_batch[b2][5]) {
            float qx2 = s_batch[b2][2], qy2 = s_batch[b2][3];
            float xx1 = fmaxf(m.x, qx1), yy1 = fmaxf(m.y, qy1);
            float xx2 = fminf(m.z, qx2), yy2 = fminf(m.w, qy2);
            float iw = fmaxf(xx2 - xx1, 0.0f), ih = fmaxf(yy2 - yy1, 0.0f);
            float inter = iw * ih;
            float aA = (qx2 - qx1) * (qy2 - qy1);
            float uni = aA + aB - inter;
            if (uni > 0.0f && inter / uni > IOU_THR) {
              int pos = atomicAdd(&s_ccnt[b2], 1);
              if (pos < KCAND) ((unsigned short*)&s_cand4[b2])[pos] = (unsigned short)c;
            }
          }
        }
      }
    }
    // ---- phase 1.5: within-batch pairwise exact-IoU masks (j < b) ----
    #pragma unroll
    for (int q = 0; q < 4; ++q) {
      int p = tid + q * NT;
      int bb2 = p >> 6, jj = p & 63;
      if (jj < bb2) {
        unsigned gb = s_bgate[bb2], gj = s_bgate[jj];
        unsigned dx = __usad(gb >> 16, gj >> 16, 0u);
        unsigned dy = __usad(gb & 0xFFFFu, gj & 0xFFFFu, 0u);
        if (dx <= 60u && dy <= 60u) {
          float ax1 = s_batch[bb2][0], ay1 = s_batch[bb2][1];
          float ax2 = s_batch[bb2][2], ay2 = s_batch[bb2][3];
          float jx1 = s_batch[jj][0], jy1 = s_batch[jj][1];
          float jx2 = s_batch[jj][2], jy2 = s_batch[jj][3];
          float xx1 = fmaxf(ax1, jx1), yy1 = fmaxf(ay1, jy1);
          float xx2 = fminf(ax2, jx2), yy2 = fminf(ay2, jy2);
          float iw = fmaxf(xx2 - xx1, 0.0f), ih = fmaxf(yy2 - yy1, 0.0f);
          float inter = iw * ih;
          float aA = (ax2 - ax1) * (ay2 - ay1);
          float aB = (jx2 - jx1) * (jy2 - jy1);
          float uni = aA + aB - inter;
          if (uni > 0.0f && inter / uni > IOU_THR)
            atomicOr(&s_pm[bb2], 1ull << jj);
        }
      }
    }
    __syncthreads();

    // ---- resolution: wave 0, flagged boxes only ----
    if (tid < 64) {
      const int lane = tid;
      float p0 = s_batch[lane][0], p1 = s_batch[lane][1], p2 = s_batch[lane][2];
      float p3 = s_batch[lane][3], p4 = s_batch[lane][4], p5 = s_batch[lane][5];
      int   cc_l = s_ccnt[lane];
      uint4 cp_l = s_cand4[lane];
      unsigned long long pm_l = s_pm[lane];
      int pml_lo = (int)(unsigned)pm_l, pml_hi = (int)(unsigned)(pm_l >> 32);
      // prefetch first candidate's state (parallel, one latency; exact: pulls are dirty-filtered)
      int c0 = (int)(cp_l.x & 0xFFFFu);
      float4 wp0 = make_float4(0.f, 0.f, 0.f, 0.f);
      float ssp0 = 1.0f; int ctp0 = 0;
      if (cc_l > 0) { wp0 = g_wsum[c0]; ssp0 = s_ssum[c0]; ctp0 = (int)s_cc[c0]; }

      unsigned long long anycand = __ballot(cc_l > 0);
      unsigned long long OVF = __ballot(cc_l > KCAND);
      unsigned long long F = __ballot(cc_l > 0 || pm_l != 0ull);
      int rs = BATCH;
      if (OVF) rs = (int)__builtin_ctzll(OVF);
      unsigned long long lowrs = (rs >= 64) ? ~0ull : ((1ull << rs) - 1ull);
      unsigned long long rem = F & lowrs;
      unsigned long long NEWM = ~F & lowrs;
      unsigned long long consumed = 0ull;

      int nmod = 0;
      int e_valid = 0, e_idx = INF, e_ct = 0, e_origbb = -1;
      float e_cls = -1.0f;
      float e_m0=0,e_m1=0,e_m2=0,e_m3=0, e_w0=0,e_w1=0,e_w2=0,e_w3=0, e_ss=0;

      while (rem) {
        int b = (int)__builtin_ctzll(rem);
        rem &= rem - 1ull;
        float bx1 = rl_f(p0, b), by1 = rl_f(p1, b);
        float bx2 = rl_f(p2, b), by2 = rl_f(p3, b);
        float sc  = rl_f(p4, b), lbf = rl_f(p5, b);

        int v = INF;
        // (a) recheck modified entries vs CURRENT state
        if (e_valid && e_cls == lbf &&
            fabsf(e_m0 - bx1) < 60.0f && fabsf(e_m1 - by1) < 60.0f) {
          float xx1 = fmaxf(e_m0, bx1), yy1 = fmaxf(e_m1, by1);
          float xx2 = fminf(e_m2, bx2), yy2 = fminf(e_m3, by2);
          float iw = fmaxf(xx2 - xx1, 0.0f), ih = fmaxf(yy2 - yy1, 0.0f);
          float inter = iw * ih;
          float aA = (bx2 - bx1) * (by2 - by1);
          float aB = (e_m2 - e_m0) * (e_m3 - e_m1);
          float uni = aA + aB - inter;
          if (uni > 0.0f && inter / uni > IOU_THR) v = e_idx;
        }
        // (b) clean pre-batch candidates (dirty-filtered)
        if ((anycand >> b) & 1ull) {
          int cc = rl_i(cc_l, b);
          unsigned w0 = (unsigned)rl_i((int)cp_l.x, b);
          unsigned w1 = (unsigned)rl_i((int)cp_l.y, b);
          unsigned w2 = (unsigned)rl_i((int)cp_l.z, b);
          unsigned w3 = (unsigned)rl_i((int)cp_l.w, b);
          if (lane < cc) {
            unsigned w = (lane >= 6) ? w3 : (lane >= 4) ? w2 : (lane >= 2) ? w1 : w0;
            int ci = (int)((w >> ((lane & 1) * 16)) & 0xFFFFu);
            if (!((s_dirty[ci >> 6] >> (ci & 63)) & 1ull)) v = min(v, ci);
          }
        }
        unsigned long long ball = __ballot(v != INF);
        int mn = INF;
        if (ball != 0ull) {
          if (__popcll(ball) == 1) {
            mn = rl_i(v, (int)__builtin_ctzll(ball));
          } else {
            int t = v;
            for (int o = 32; o; o >>= 1) t = min(t, __shfl_xor(t, o));
            mn = t;
          }
        }
        // (c) within-batch singleton pair candidate
        unsigned long long pc =
            (((unsigned long long)(unsigned)rl_i(pml_hi, b)) << 32) |
            (unsigned long long)(unsigned)rl_i(pml_lo, b);
        pc &= ~F & ~consumed;
        int pj = 64, pairidx = INF;
        if (pc) {
          pj = (int)__builtin_ctzll(pc);
          pairidx = nm0 + (int)__builtin_popcountll(NEWM & ((1ull << pj) - 1ull));
        }
        if (pairidx < mn) mn = pairidx;

        if (mn == INF) {
          int nidx = nm0 + (int)__builtin_popcountll(NEWM & ((1ull << b) - 1ull));
          NEWM |= 1ull << b;
          if (lane == nmod) {
            e_valid = 1; e_idx = nidx; e_cls = lbf; e_origbb = -1;
            e_w0 = sc * bx1; e_w1 = sc * by1; e_w2 = sc * bx2; e_w3 = sc * by2;
            e_ss = sc; e_ct = 1;
            e_m0 = e_w0 / e_ss; e_m1 = e_w1 / e_ss; e_m2 = e_w2 / e_ss; e_m3 = e_w3 / e_ss;
          }
          nmod++;
        } else {
          bool mine = e_valid && (e_idx == mn);
          unsigned long long mb = __ballot(mine);
          int owner;
          if (mb != 0ull) {
            owner = (int)__builtin_ctzll(mb);
            if (mine) {
              e_w0 += sc * bx1; e_w1 += sc * by1; e_w2 += sc * bx2; e_w3 += sc * by2;
              e_ss += sc; e_ct += 1;
              e_m0 = e_w0 / e_ss; e_m1 = e_w1 / e_ss; e_m2 = e_w2 / e_ss; e_m3 = e_w3 / e_ss;
            }
          } else if (mn < nm0) {
            owner = nmod;
            int rc0 = rl_i(c0, b);   // uniform: prefetched cand0 of box b
            if (lane == nmod) {      // pull clean cluster
              float w0, w1, w2, w3, ss; int ctp;
              if (mn == rc0) {
                w0 = rl_f(wp0.x, b); w1 = rl_f(wp0.y, b);
                w2 = rl_f(wp0.z, b); w3 = rl_f(wp0.w, b);
                ss = rl_f(ssp0, b);  ctp = rl_i(ctp0, b);
              } else {
                float4 w = g_wsum[mn];
                w0 = w.x; w1 = w.y; w2 = w.z; w3 = w.w;
                ss = s_ssum[mn]; ctp = (int)s_cc[mn];
              }
              e_valid = 1; e_idx = mn; e_cls = lbf;
              e_origbb = ((int)(w0 / ss)) >> 8;     // == bin(old m.x), bitwise-same divide
              e_w0 = w0 + sc * bx1; e_w1 = w1 + sc * by1;
              e_w2 = w2 + sc * bx2; e_w3 = w3 + sc * by2;
              e_ss = ss + sc; e_ct = (ctp & 0x3FFF) + 1;
              e_m0 = e_w0 / e_ss; e_m1 = e_w1 / e_ss; e_m2 = e_w2 / e_ss; e_m3 = e_w3 / e_ss;
              atomicOr(&s_dirty[mn >> 6], 1ull << (mn & 63));
            }
            nmod++;
          } else {
            owner = nmod;                           // pull unflagged singleton pj
            consumed |= 1ull << pj;
            if (lane == nmod) {
              float jx1 = rl_f(p0, pj), jy1 = rl_f(p1, pj);
              float jx2 = rl_f(p2, pj), jy2 = rl_f(p3, pj);
              float jsc = rl_f(p4, pj);
              e_valid = 1; e_idx = mn; e_cls = lbf; e_origbb = -1;
              e_w0 = jsc * jx1 + sc * bx1; e_w1 = jsc * jy1 + sc * by1;
              e_w2 = jsc * jx2 + sc * bx2; e_w3 = jsc * jy2 + sc * by2;
              e_ss = jsc + sc; e_ct = 2;
              e_m0 = e_w0 / e_ss; e_m1 = e_w1 / e_ss; e_m2 = e_w2 / e_ss; e_m3 = e_w3 / e_ss;
            }
            nmod++;
          }
          // detection: did this merge capture a later unflagged box?
          float nx1 = rl_f(e_m0, owner), ny1 = rl_f(e_m1, owner);
          float nx2 = rl_f(e_m2, owner), ny2 = rl_f(e_m3, owner);
          bool dp = false;
          if (p5 == lbf) {
            float xx1 = fmaxf(nx1, p0), yy1 = fmaxf(ny1, p1);
            float xx2 = fminf(nx2, p2), yy2 = fminf(ny2, p3);
            float iw = fmaxf(xx2 - xx1, 0.0f), ih = fmaxf(yy2 - yy1, 0.0f);
            float inter = iw * ih;
            float aA = (p2 - p0) * (p3 - p1);
            float aB = (nx2 - nx1) * (ny2 - ny1);
            float uni = aA + aB - inter;
            dp = (uni > 0.0f) && (inter / uni > IOU_THR);
          }
          unsigned long long det = __ballot(dp);
          unsigned long long himask = (b >= 63) ? 0ull : (~0ull << (b + 1));
          det &= ~F & ~consumed & lowrs & himask;
          if (det) { F |= det; rem |= det; NEWM &= ~det; }
        }
      }

      // writeback modified entries (+ bucket invariant maintenance)
      if (e_valid) {
        s_mbox[e_idx] = make_float4(e_m0, e_m1, e_m2, e_m3);
        g_wsum[e_idx] = make_float4(e_w0, e_w1, e_w2, e_w3);
        s_ssum[e_idx] = e_ss;
        s_cc[e_idx] = (unsigned short)(e_ct | (((int)e_cls) << 14));
        int nb = ((int)e_m0) >> 8;
        if (nb < 0) nb = 0; if (nb > NBINS - 1) nb = NBINS - 1;
        if (nb != e_origbb) {
          int bk = ((int)e_cls) * NBINS + nb;
          int p = atomicAdd(&s_bktlen[bk], 1);
          if (p < BCAP) s_bkt[bk][p] = (unsigned short)e_idx; else s_ovf = 1;
        }
      }
      // bulk-materialize untouched singletons
      {
        unsigned long long selfbit = 1ull << lane;
        if (NEWM & ~F & ~consumed & selfbit) {
          int idx = nm0 + (int)__builtin_popcountll(NEWM & (selfbit - 1ull));
          float w0 = p4 * p0, w1 = p4 * p1, w2 = p4 * p2, w3 = p4 * p3;
          float m0 = w0 / p4, m1 = w1 / p4, m2 = w2 / p4, m3 = w3 / p4;
          g_wsum[idx] = make_float4(w0, w1, w2, w3);
          s_ssum[idx] = p4;
          s_cc[idx] = (unsigned short)(1 | (((int)p5) << 14));
          s_mbox[idx] = make_float4(m0, m1, m2, m3);
          int nb = ((int)m0) >> 8;
          if (nb < 0) nb = 0; if (nb > NBINS - 1) nb = NBINS - 1;
          int bk = ((int)p5) * NBINS + nb;
          int p = atomicAdd(&s_bktlen[bk], 1);
          if (p < BCAP) s_bkt[bk][p] = (unsigned short)idx; else s_ovf = 1;
        }
      }
      s_dirty[lane] = 0ull;
      if (lane == 0) {
        s_num = nm0 + (int)__builtin_popcountll(NEWM);
        s_resume = rs;
      }
    }
    __syncthreads();

    // ---- exact serial fallback (candidate overflow; rare) ----
    int rs2 = s_resume;
    if (rs2 < BATCH) {
      for (int i = rs2; i < BATCH; ++i) {
        float bx1 = s_batch[i][0], by1 = s_batch[i][1];
        float bx2 = s_batch[i][2], by2 = s_batch[i][3];
        float sc  = s_batch[i][4];
        int lb = (int)s_batch[i][5];
        int nm = s_num;
        float aA = (bx2 - bx1) * (by2 - by1);
        int mymin = INF;
        for (int c = tid; c < nm; c += NT) {
          float4 m = s_mbox[c];
          if (fabsf(m.x - bx1) < 60.0f && fabsf(m.y - by1) < 60.0f &&
              (int)(s_cc[c] >> 14) == lb) {
            float xx1 = fmaxf(m.x, bx1), yy1 = fmaxf(m.y, by1);
            float xx2 = fminf(m.z, bx2), yy2 = fminf(m.w, by2);
            float iw = fmaxf(xx2 - xx1, 0.0f), ih = fmaxf(yy2 - yy1, 0.0f);
            float inter = iw * ih;
            float aB = (m.z - m.x) * (m.w - m.y);
            float uni = aA + aB - inter;
            if (uni > 0.0f && inter / uni > IOU_THR) mymin = min(mymin, c);
          }
        }
        if (mymin != INF) atomicMin(&s_min[i & 1], mymin);
        __syncthreads();
        int mn = s_min[i & 1];
        if (tid == 0) {
          s_min[(i + 1) & 1] = INF;
          bool has = (mn != INF);
          int idx = has ? mn : nm;
          float w0, w1, w2, w3, ss; int ct, ob = -1;
          if (has) {
            float4 w = g_wsum[idx];
            w0 = w.x; w1 = w.y; w2 = w.z; w3 = w.w;
            ss = s_ssum[idx]; ct = (int)(s_cc[idx] & 0x3FFF);
            ob = ((int)s_mbox[idx].x) >> 8;
          } else { w0 = w1 = w2 = w3 = 0.0f; ss = 0.0f; ct = 0; }
          w0 += sc * bx1; w1 += sc * by1; w2 += sc * bx2; w3 += sc * by2;
          ss += sc; ct += 1;
          float m0 = w0 / ss, m1 = w1 / ss, m2 = w2 / ss, m3 = w3 / ss;
          g_wsum[idx] = make_float4(w0, w1, w2, w3);
          s_ssum[idx] = ss;
          s_cc[idx] = (unsigned short)(ct | (lb << 14));
          s_mbox[idx] = make_float4(m0, m1, m2, m3);
          int nb = ((int)m0) >> 8;
          if (nb < 0) nb = 0; if (nb > NBINS - 1) nb = NBINS - 1;
          if (nb != ob) {
            int bk = lb * NBINS + nb;
            int p = atomicAdd(&s_bktlen[bk], 1);
            if (p < BCAP) s_bkt[bk][p] = (unsigned short)idx; else s_ovf = 1;
          }
          if (!has) s_num = nm + 1;
        }
        __syncthreads();
      }
      if (tid == 0) { s_min[0] = INF; s_min[1] = INF; }
    }
  }

  // ================= scoring + sort keys (keys alias s_mbox) =================
  __syncthreads();
  unsigned long long* s_keys = (unsigned long long*)s_mbox;
  int num = s_num;
  for (int j = tid; j < N; j += NT) {
    unsigned int lo = ~(unsigned int)j;              // lower index wins ties
    unsigned long long key;
    if (j < num) {
      float ct = (float)(s_cc[j] & 0x3FFF);
      float sco = s_ssum[j] / fmaxf(ct, 1.0f);       // bitwise == reference score
      unsigned int bb = __float_as_uint(sco) | 0x80000000u;
      key = ((unsigned long long)bb << 32) | lo;
    } else {
      key = (0x407FFFFFull << 32) | lo;              // mapped bits of -1.0f sort key
    }
    s_keys[j] = key;
  }
  __syncthreads();

  // ---- bitonic sort, descending, 4096 u64 keys ----
  for (int k = 2; k <= N; k <<= 1) {
    for (int j = k >> 1; j > 0; j >>= 1) {
      #pragma unroll
      for (int w = 0; w < N / NT; ++w) {
        int a0 = tid + (w << 10);
        int l = a0 ^ j;
        if (l > a0) {
          unsigned long long a = s_keys[a0], bq = s_keys[l];
          bool desc = ((a0 & k) == 0);
          bool sw = desc ? (a < bq) : (a > bq);
          if (sw) { s_keys[a0] = bq; s_keys[l] = a; }
        }
      }
      __syncthreads();
    }
  }

  // ---- emit top-1000 rows (box = g_wsum/ssum, bitwise == stored mbox) ----
  if (tid < 1000) {
    unsigned long long key = s_keys[tid];
    unsigned int hi = (unsigned int)(key >> 32);
    float* o = out + (size_t)tid * 6;
    if (hi & 0x80000000u) {
      int j = (int)(~(unsigned int)key);
      float4 w = g_wsum[j];
      float ss = s_ssum[j];
      o[0] = w.x / ss; o[1] = w.y / ss; o[2] = w.z / ss; o[3] = w.w / ss;
      o[4] = __uint_as_float(hi & 0x7FFFFFFFu);
      o[5] = (float)(s_cc[j] >> 14);
    } else {
      o[0] = 0.0f; o[1] = 0.0f; o[2] = 0.0f;
      o[3] = 0.0f; o[4] = 0.0f; o[5] = 0.0f;
    }
  }
}

extern "C" void kernel_launch(void* const* d_in, const int* in_sizes, int n_in,
                              void* d_out, int out_size, void* d_ws, size_t ws_size,
                              hipStream_t stream) {
  const float* boxes = (const float*)d_in[0];
  const float* offs  = (const float*)d_in[1];
  float* out = (float*)d_out;
  hipLaunchKernelGGL(wbf_kernel, dim3(1), dim3(NT), 0, stream, boxes, offs, out);
}